// Round 5
// baseline (288.399 us; speedup 1.0000x reference)
//
#include <hip/hip_runtime.h>
#include <stdint.h>

// Problem constants
//   B=32, SQ=SK=512, DIM=512, H=8, HD=64, SCALE=0.125

typedef unsigned short u16;
typedef __attribute__((ext_vector_type(4))) float f32x4;
typedef __attribute__((ext_vector_type(8))) __bf16 bf16x8;
typedef __attribute__((ext_vector_type(4))) unsigned short u16x4;
typedef __attribute__((ext_vector_type(8))) unsigned short u16x8;
typedef __attribute__((ext_vector_type(4))) int i32x4;
typedef __attribute__((ext_vector_type(4))) _Float16 f16x4;
typedef __attribute__((ext_vector_type(8))) _Float16 f16x8;

#define MFMA16(a, b, c) __builtin_amdgcn_mfma_f32_16x16x32_bf16((a), (b), (c), 0, 0, 0)

__device__ __forceinline__ u16 f2bf(float f) {
  unsigned u = __float_as_uint(f);
  u += 0x7fffu + ((u >> 16) & 1u);   // RNE
  return (u16)(u >> 16);
}
__device__ __forceinline__ float bf2f(u16 h) {
  return __uint_as_float(((unsigned)h) << 16);
}

// ---------------------------------------------------------------------------
// K0: weight prep. Wt[mat][n][k] = bf16(W[k][n]) for q,k,v; Wo -> hi/lo split,
// transposed to [n][k].
// ---------------------------------------------------------------------------
__global__ __launch_bounds__(256) void k_prep(
    const float* __restrict__ Wq, const float* __restrict__ Wk,
    const float* __restrict__ Wv, const float* __restrict__ Wo,
    u16* __restrict__ Wt, u16* __restrict__ WoHi, u16* __restrict__ WoLo) {
  int idx = blockIdx.x * 256 + threadIdx.x;   // 0..262143, k-major within n
  int n = idx >> 9, k = idx & 511;
  int src = k * 512 + n;                      // W[k][n]
  Wt[idx]          = f2bf(Wq[src]);
  Wt[262144 + idx] = f2bf(Wk[src]);
  Wt[524288 + idx] = f2bf(Wv[src]);
  float wo = Wo[src];
  u16 hi = f2bf(wo);
  WoHi[idx] = hi;
  WoLo[idx] = f2bf(wo - bf2f(hi));
}

// ---------------------------------------------------------------------------
// K0b: fused mask+bias -> fp16. MB[b][sq][sk] = mask ? fp16(bias) : -60000.
// ---------------------------------------------------------------------------
__global__ __launch_bounds__(256) void k_mb(
    const int* __restrict__ mask, const float* __restrict__ bias,
    _Float16* __restrict__ MB) {
  size_t i8 = ((size_t)blockIdx.x * 256 + threadIdx.x) * 8;
  i32x4 m0 = *(const i32x4*)&mask[i8];
  i32x4 m1 = *(const i32x4*)&mask[i8 + 4];
  size_t bi = i8 & 262143;                    // idx % (512*512), bias broadcast over b
  f32x4 b0 = *(const f32x4*)&bias[bi];
  f32x4 b1 = *(const f32x4*)&bias[bi + 4];
  const _Float16 MASKED = (_Float16)(-60000.0f);
  f16x8 o;
#pragma unroll
  for (int e = 0; e < 4; ++e) {
    o[e]     = (m0[e] != 0) ? (_Float16)b0[e] : MASKED;
    o[e + 4] = (m1[e] != 0) ? (_Float16)b1[e] : MASKED;
  }
  *(f16x8*)&MB[i8] = o;
}

// ---------------------------------------------------------------------------
// K1: projections. C[16384x512] = X[16384x512] @ W[512x512], per mat in z.
// Block 512 thr (8 waves, 2x4), tile 128x256, BK=32.
// Q,K stored bf16 [b,h,sq,hd]; V stored transposed bf16 [b,h,hd,sk].
// ---------------------------------------------------------------------------
__global__ __launch_bounds__(512) void k_proj(
    const float* __restrict__ Xq, const float* __restrict__ Xk, const float* __restrict__ Xv,
    const u16* __restrict__ Wt,
    u16* __restrict__ Qb, u16* __restrict__ Kb, u16* __restrict__ Vtb) {
  __shared__ u16 lA[128][40];
  __shared__ u16 lB[256][40];
  const int mat = blockIdx.z;
  const float* __restrict__ A = (mat == 0) ? Xq : (mat == 1) ? Xk : Xv;
  const u16* __restrict__ Bw = Wt + (size_t)mat * 262144;
  const int tid = threadIdx.x;
  const int lane = tid & 63, wid = tid >> 6;
  const int wm = wid >> 2, wn = wid & 3;       // wave grid 2 x 4
  const int m0 = blockIdx.y * 128, n0 = blockIdx.x * 256;
  const int fr = lane & 15, g = lane >> 4;
  const int arow = tid >> 3, acg = tid & 7;
  f32x4 acc[4][4] = {};

  for (int kt = 0; kt < 16; ++kt) {
    const int k0 = kt * 32;
#pragma unroll
    for (int p = 0; p < 2; ++p) {              // A: fp32 -> bf16 reg-stage
      int row = p * 64 + arow;
      f32x4 v = *(const f32x4*)&A[(size_t)(m0 + row) * 512 + k0 + acg * 4];
      u16x4 hv;
      hv[0] = f2bf(v[0]); hv[1] = f2bf(v[1]); hv[2] = f2bf(v[2]); hv[3] = f2bf(v[3]);
      *(u16x4*)&lA[row][acg * 4] = hv;
    }
#pragma unroll
    for (int p = 0; p < 2; ++p) {              // B: bf16 copy (row-major [n][k])
      int idx = p * 512 + tid;
      int row = idx >> 2, cg = idx & 3;
      *(u16x8*)&lB[row][cg * 8] = *(const u16x8*)&Bw[(size_t)(n0 + row) * 512 + k0 + cg * 8];
    }
    __syncthreads();
    bf16x8 af[4], bfr[4];
#pragma unroll
    for (int fm = 0; fm < 4; ++fm)
      af[fm] = *(const bf16x8*)&lA[wm * 64 + fm * 16 + fr][g * 8];
#pragma unroll
    for (int fn = 0; fn < 4; ++fn)
      bfr[fn] = *(const bf16x8*)&lB[wn * 64 + fn * 16 + fr][g * 8];
#pragma unroll
    for (int fm = 0; fm < 4; ++fm)
#pragma unroll
      for (int fn = 0; fn < 4; ++fn)
        acc[fm][fn] = MFMA16(af[fm], bfr[fn], acc[fm][fn]);
    __syncthreads();
  }

  if (mat < 2) {
    u16* __restrict__ Out = (mat == 0) ? Qb : Kb;
#pragma unroll
    for (int fm = 0; fm < 4; ++fm) {
#pragma unroll
      for (int fn = 0; fn < 4; ++fn) {
        int gn = n0 + wn * 64 + fn * 16 + fr;
        int hh = gn >> 6, hd = gn & 63;
#pragma unroll
        for (int r = 0; r < 4; ++r) {
          int gm = m0 + wm * 64 + fm * 16 + g * 4 + r;
          int b = gm >> 9, sq = gm & 511;
          Out[(size_t)((b * 8 + hh) * 512 + sq) * 64 + hd] = f2bf(acc[fm][fn][r]);
        }
      }
    }
  } else {
#pragma unroll
    for (int fm = 0; fm < 4; ++fm) {
      int gm0 = m0 + wm * 64 + fm * 16 + g * 4;
      int b = gm0 >> 9, sq0 = gm0 & 511;
#pragma unroll
      for (int fn = 0; fn < 4; ++fn) {
        int gn = n0 + wn * 64 + fn * 16 + fr;
        int hh = gn >> 6, hd = gn & 63;
        u16x4 pv;
        pv[0] = f2bf(acc[fm][fn][0]); pv[1] = f2bf(acc[fm][fn][1]);
        pv[2] = f2bf(acc[fm][fn][2]); pv[3] = f2bf(acc[fm][fn][3]);
        *(u16x4*)&Vtb[(size_t)((b * 8 + hh) * 64 + hd) * 512 + sq0] = pv;
      }
    }
  }
}

// ---------------------------------------------------------------------------
// K2: attention, swapped QK^T (mfma(K,Q)). 16 q-rows per wave, 4 waves/block,
// grid = 32b x 8h x 8qo = 2048 blocks (8/CU available, launch_bounds(256,6)).
// P bounce: [16][64] u16 rows, byte-XOR swizzle ((fr&7)<<4) -> write 2-way
// free, read at the b128 8-beat floor. Defer-max (T13, THR=8) skips the
// O-rescale on most tiles. Scores = 0.125*QK + MB (fp16 bias or -60000).
// b-slow XCD swizzle keeps one batch's ~2MB (Q/K/V/MB) per XCD in L2.
// ---------------------------------------------------------------------------
__global__ __launch_bounds__(256, 6) void k_attn(
    const u16* __restrict__ Qb, const u16* __restrict__ Kb, const u16* __restrict__ Vtb,
    const _Float16* __restrict__ MB, float* __restrict__ Obuf) {
  __shared__ __align__(16) u16 lP[4][16][64];   // 8KB
  const int tid = threadIdx.x, lane = tid & 63, w = tid >> 6;
  const int orig = blockIdx.x;
  const int xcd = orig & 7, idx = orig >> 3;    // idx 0..255
  const int b = xcd + 8 * (idx >> 6);           // b slow-varying per XCD
  const int h = (idx >> 3) & 7, qo = idx & 7;   // head, q-octant
  const int bh = b * 8 + h;
  const int fr = lane & 15, g = lane >> 4;
  const int sq0 = qo * 64 + w * 16;
  const int sw = (fr & 7) << 4;                 // byte XOR swizzle
  const u16* __restrict__ Qh = Qb + (size_t)bh * 32768;
  const u16* __restrict__ Kh = Kb + (size_t)bh * 32768;
  const u16* __restrict__ Vh = Vtb + (size_t)bh * 32768;
  const _Float16* __restrict__ MBr = MB + (size_t)b * 262144 + (size_t)(sq0 + fr) * 512;
  char* lProw = (char*)&lP[w][fr][0];

  // Q fragments (B operand): row = sq0+fr, k = kc*32+g*8
  bf16x8 qf[2];
  qf[0] = *(const bf16x8*)&Qh[(size_t)(sq0 + fr) * 64 + g * 8];
  qf[1] = *(const bf16x8*)&Qh[(size_t)(sq0 + fr) * 64 + 32 + g * 8];

  f32x4 oacc[4] = {};
  float mrow = -1e30f, lrow = 0.f;

  for (int kt = 0; kt < 8; ++kt) {
    const int sk0 = kt * 64;
    // masked-bias loads (8B per lane, issued early, overlap QK MFMA)
    f16x4 mbv[4];
#pragma unroll
    for (int fn = 0; fn < 4; ++fn)
      mbv[fn] = *(const f16x4*)&MBr[sk0 + fn * 16 + g * 4];
    // QK^T swapped: lane holds q = sq0+fr (col), sk = fn*16+g*4+r (row)
    f32x4 sacc[4] = {};
#pragma unroll
    for (int fn = 0; fn < 4; ++fn) {
      const u16* kr = &Kh[(size_t)(sk0 + fn * 16 + fr) * 64 + g * 8];
      bf16x8 kf0 = *(const bf16x8*)kr;
      bf16x8 kf1 = *(const bf16x8*)(kr + 32);
      sacc[fn] = MFMA16(kf0, qf[0], sacc[fn]);
      sacc[fn] = MFMA16(kf1, qf[1], sacc[fn]);
    }
    // scale + masked bias
#pragma unroll
    for (int fn = 0; fn < 4; ++fn)
#pragma unroll
      for (int r = 0; r < 4; ++r)
        sacc[fn][r] = sacc[fn][r] * 0.125f + (float)mbv[fn][r];

    // online softmax: in-lane reduce over 16 regs + xor16/xor32
    float t0 = fmaxf(fmaxf(sacc[0][0], sacc[0][1]), fmaxf(sacc[0][2], sacc[0][3]));
    float t1 = fmaxf(fmaxf(sacc[1][0], sacc[1][1]), fmaxf(sacc[1][2], sacc[1][3]));
    float t2 = fmaxf(fmaxf(sacc[2][0], sacc[2][1]), fmaxf(sacc[2][2], sacc[2][3]));
    float t3 = fmaxf(fmaxf(sacc[3][0], sacc[3][1]), fmaxf(sacc[3][2], sacc[3][3]));
    float pm = fmaxf(fmaxf(t0, t1), fmaxf(t2, t3));
    pm = fmaxf(pm, __shfl_xor(pm, 16));
    pm = fmaxf(pm, __shfl_xor(pm, 32));
    if (!__all(pm - mrow <= 8.0f)) {          // defer-max (T13): rescale rarely
      float mn = fmaxf(mrow, pm);
      float sfac = __expf(mrow - mn);
      mrow = mn;
      lrow *= sfac;
#pragma unroll
      for (int r = 0; r < 4; ++r) {
        float sr = __shfl(sfac, g * 4 + r);   // sfac uniform across g
#pragma unroll
        for (int fnh = 0; fnh < 4; ++fnh)
          oacc[fnh][r] *= sr;
      }
    }
    float ps = 0.f;
#pragma unroll
    for (int fn = 0; fn < 4; ++fn) {
      float p0 = __expf(sacc[fn][0] - mrow);
      float p1 = __expf(sacc[fn][1] - mrow);
      float p2 = __expf(sacc[fn][2] - mrow);
      float p3 = __expf(sacc[fn][3] - mrow);
      ps += (p0 + p1) + (p2 + p3);
      u16x4 pw;
      pw[0] = f2bf(p0); pw[1] = f2bf(p1); pw[2] = f2bf(p2); pw[3] = f2bf(p3);
      *(u16x4*)(lProw + ((fn * 32 + g * 8) ^ sw)) = pw;   // swizzled b64 write
    }
    ps += __shfl_xor(ps, 16);
    ps += __shfl_xor(ps, 32);
    lrow += ps;
    __builtin_amdgcn_wave_barrier();   // P writes before P reads (wave-private)
    // PV: A = P (swizzled LDS read), B = V fragments
#pragma unroll
    for (int kc = 0; kc < 2; ++kc) {
      bf16x8 pf = *(const bf16x8*)(lProw + ((kc * 64 + g * 16) ^ sw));
#pragma unroll
      for (int fnh = 0; fnh < 4; ++fnh) {
        bf16x8 vf = *(const bf16x8*)&Vh[(size_t)(fnh * 16 + fr) * 512 + sk0 + kc * 32 + g * 8];
        oacc[fnh] = MFMA16(pf, vf, oacc[fnh]);
      }
    }
    __builtin_amdgcn_wave_barrier();   // next kt's P writes after these reads
  }
  // epilogue: O / l -> Obuf[b, sq, h*64+hd] fp32 (oacc: q = g*4+r, d = fnh*16+fr)
#pragma unroll
  for (int r = 0; r < 4; ++r) {
    float lr = __shfl(lrow, g * 4 + r);
    float inv = 1.0f / lr;
    const int sq = sq0 + g * 4 + r;
    float* orow = &Obuf[((size_t)b * 512 + sq) * 512 + h * 64];
#pragma unroll
    for (int fnh = 0; fnh < 4; ++fnh)
      orow[fnh * 16 + fr] = oacc[fnh][r] * inv;
  }
}

// ---------------------------------------------------------------------------
// K3: output projection with 2-term bf16 split (hi/lo) for fp32-level accuracy:
// C = Oh@Wh + Oh@Wl + Ol@Wh + bo. Tile 128x256, 8 waves.
// ---------------------------------------------------------------------------
__global__ __launch_bounds__(512) void k_out(
    const float* __restrict__ Oin, const u16* __restrict__ WoHi, const u16* __restrict__ WoLo,
    const float* __restrict__ bo, float* __restrict__ out) {
  __shared__ u16 lAh[128][40], lAl[128][40];
  __shared__ u16 lBh[256][40], lBl[256][40];
  const int tid = threadIdx.x;
  const int lane = tid & 63, wid = tid >> 6;
  const int wm = wid >> 2, wn = wid & 3;
  const int m0 = blockIdx.y * 128, n0 = blockIdx.x * 256;
  const int fr = lane & 15, g = lane >> 4;
  const int arow = tid >> 3, acg = tid & 7;
  f32x4 acc[4][4] = {};

  for (int kt = 0; kt < 16; ++kt) {
    const int k0 = kt * 32;
#pragma unroll
    for (int p = 0; p < 2; ++p) {
      int row = p * 64 + arow;
      f32x4 v = *(const f32x4*)&Oin[(size_t)(m0 + row) * 512 + k0 + acg * 4];
      u16x4 hv, lv;
#pragma unroll
      for (int e = 0; e < 4; ++e) {
        u16 hb = f2bf(v[e]);
        hv[e] = hb;
        lv[e] = f2bf(v[e] - bf2f(hb));
      }
      *(u16x4*)&lAh[row][acg * 4] = hv;
      *(u16x4*)&lAl[row][acg * 4] = lv;
    }
#pragma unroll
    for (int p = 0; p < 2; ++p) {
      int idx = p * 512 + tid;
      int row = idx >> 2, cg = idx & 3;
      *(u16x8*)&lBh[row][cg * 8] = *(const u16x8*)&WoHi[(size_t)(n0 + row) * 512 + k0 + cg * 8];
      *(u16x8*)&lBl[row][cg * 8] = *(const u16x8*)&WoLo[(size_t)(n0 + row) * 512 + k0 + cg * 8];
    }
    __syncthreads();
    bf16x8 ah[4], al[4];
#pragma unroll
    for (int fm = 0; fm < 4; ++fm) {
      ah[fm] = *(const bf16x8*)&lAh[wm * 64 + fm * 16 + fr][g * 8];
      al[fm] = *(const bf16x8*)&lAl[wm * 64 + fm * 16 + fr][g * 8];
    }
#pragma unroll
    for (int fn = 0; fn < 4; ++fn) {
      bf16x8 bh = *(const bf16x8*)&lBh[wn * 64 + fn * 16 + fr][g * 8];
      bf16x8 bl = *(const bf16x8*)&lBl[wn * 64 + fn * 16 + fr][g * 8];
#pragma unroll
      for (int fm = 0; fm < 4; ++fm) {
        acc[fm][fn] = MFMA16(ah[fm], bh, acc[fm][fn]);
        acc[fm][fn] = MFMA16(ah[fm], bl, acc[fm][fn]);
        acc[fm][fn] = MFMA16(al[fm], bh, acc[fm][fn]);
      }
    }
    __syncthreads();
  }
#pragma unroll
  for (int fm = 0; fm < 4; ++fm) {
#pragma unroll
    for (int fn = 0; fn < 4; ++fn) {
      int gn = n0 + wn * 64 + fn * 16 + fr;
      float bv = bo[gn];
#pragma unroll
      for (int r = 0; r < 4; ++r) {
        int gm = m0 + wm * 64 + fm * 16 + g * 4 + r;
        out[(size_t)gm * 512 + gn] = acc[fm][fn][r] + bv;
      }
    }
  }
}

// ---------------------------------------------------------------------------
extern "C" void kernel_launch(void* const* d_in, const int* in_sizes, int n_in,
                              void* d_out, int out_size, void* d_ws, size_t ws_size,
                              hipStream_t stream) {
  (void)in_sizes; (void)n_in; (void)out_size; (void)ws_size;
  const float* query = (const float*)d_in[0];
  const float* key_t = (const float*)d_in[1];
  const float* value = (const float*)d_in[2];
  const int*   mask  = (const int*)d_in[3];
  const float* Wq    = (const float*)d_in[4];
  const float* Wk    = (const float*)d_in[5];
  const float* Wv    = (const float*)d_in[6];
  const float* Wo    = (const float*)d_in[7];
  const float* bo    = (const float*)d_in[8];
  const float* bias  = (const float*)d_in[9];
  float* out = (float*)d_out;

  char* p = (char*)d_ws;
  u16* Wt   = (u16*)p; p += (size_t)3 * 512 * 512 * 2;       // 1.5 MB
  u16* WoHi = (u16*)p; p += (size_t)512 * 512 * 2;           // 0.5 MB
  u16* WoLo = (u16*)p; p += (size_t)512 * 512 * 2;           // 0.5 MB
  u16* Qb   = (u16*)p; p += (size_t)32 * 8 * 512 * 64 * 2;   // 16.8 MB
  u16* Kb   = (u16*)p; p += (size_t)32 * 8 * 512 * 64 * 2;   // 16.8 MB
  u16* Vtb  = (u16*)p; p += (size_t)32 * 8 * 512 * 64 * 2;   // 16.8 MB
  float* Obuf = (float*)p; p += (size_t)32 * 512 * 512 * 4;  // 33.5 MB
  _Float16* MBp = (_Float16*)p;                              // 16.8 MB (total ~103.6 MB)

  k_prep<<<1024, 256, 0, stream>>>(Wq, Wk, Wv, Wo, Wt, WoHi, WoLo);
  k_mb<<<4096, 256, 0, stream>>>(mask, bias, MBp);
  k_proj<<<dim3(2, 128, 3), 512, 0, stream>>>(query, key_t, value, Wt, Qb, Kb, Vtb);
  k_attn<<<2048, 256, 0, stream>>>(Qb, Kb, Vtb, MBp, Obuf);
  k_out<<<dim3(2, 128), 512, 0, stream>>>(Obuf, WoHi, WoLo, bo, out);
}

// Round 6
// 185.362 us; speedup vs baseline: 1.5559x; 1.5559x over previous
//
#include <hip/hip_runtime.h>
#include <stdint.h>

// Problem constants
//   B=32, SQ=SK=512, DIM=512, H=8, HD=64, SCALE=0.125

typedef unsigned short u16;
typedef __attribute__((ext_vector_type(4))) float f32x4;
typedef __attribute__((ext_vector_type(8))) __bf16 bf16x8;
typedef __attribute__((ext_vector_type(4))) unsigned short u16x4;
typedef __attribute__((ext_vector_type(8))) unsigned short u16x8;
typedef __attribute__((ext_vector_type(4))) int i32x4;
typedef __attribute__((ext_vector_type(4))) _Float16 f16x4;
typedef __attribute__((ext_vector_type(8))) _Float16 f16x8;

#define MFMA16(a, b, c) __builtin_amdgcn_mfma_f32_16x16x32_bf16((a), (b), (c), 0, 0, 0)

__device__ __forceinline__ u16 f2bf(float f) {
  unsigned u = __float_as_uint(f);
  u += 0x7fffu + ((u >> 16) & 1u);   // RNE
  return (u16)(u >> 16);
}
__device__ __forceinline__ float bf2f(u16 h) {
  return __uint_as_float(((unsigned)h) << 16);
}

// async global->LDS, 16B per lane. LDS dest = wave-uniform base + lane*16
// (linear); swizzling is done on the GLOBAL source address (rule #21).
__device__ __forceinline__ void gl_lds16(const void* g, void* l) {
  __builtin_amdgcn_global_load_lds(
      (const __attribute__((address_space(1))) unsigned int*)g,
      (__attribute__((address_space(3))) unsigned int*)l, 16, 0, 0);
}

// ---------------------------------------------------------------------------
// K0: weight prep. Wt[mat][n][k] = bf16(W[k][n]) for q,k,v; Wo -> hi/lo split,
// transposed to [n][k].
// ---------------------------------------------------------------------------
__global__ __launch_bounds__(256) void k_prep(
    const float* __restrict__ Wq, const float* __restrict__ Wk,
    const float* __restrict__ Wv, const float* __restrict__ Wo,
    u16* __restrict__ Wt, u16* __restrict__ WoHi, u16* __restrict__ WoLo) {
  int idx = blockIdx.x * 256 + threadIdx.x;   // 0..262143, k-major within n
  int n = idx >> 9, k = idx & 511;
  int src = k * 512 + n;                      // W[k][n]
  Wt[idx]          = f2bf(Wq[src]);
  Wt[262144 + idx] = f2bf(Wk[src]);
  Wt[524288 + idx] = f2bf(Wv[src]);
  float wo = Wo[src];
  u16 hi = f2bf(wo);
  WoHi[idx] = hi;
  WoLo[idx] = f2bf(wo - bf2f(hi));
}

// ---------------------------------------------------------------------------
// K0b: fused mask+bias -> fp16. MB[b][sq][sk] = mask ? fp16(bias) : -60000.
// ---------------------------------------------------------------------------
__global__ __launch_bounds__(256) void k_mb(
    const int* __restrict__ mask, const float* __restrict__ bias,
    _Float16* __restrict__ MB) {
  size_t i8 = ((size_t)blockIdx.x * 256 + threadIdx.x) * 8;
  i32x4 m0 = *(const i32x4*)&mask[i8];
  i32x4 m1 = *(const i32x4*)&mask[i8 + 4];
  size_t bi = i8 & 262143;                    // idx % (512*512), bias broadcast over b
  f32x4 b0 = *(const f32x4*)&bias[bi];
  f32x4 b1 = *(const f32x4*)&bias[bi + 4];
  const _Float16 MASKED = (_Float16)(-60000.0f);
  f16x8 o;
#pragma unroll
  for (int e = 0; e < 4; ++e) {
    o[e]     = (m0[e] != 0) ? (_Float16)b0[e] : MASKED;
    o[e + 4] = (m1[e] != 0) ? (_Float16)b1[e] : MASKED;
  }
  *(f16x8*)&MB[i8] = o;
}

// ---------------------------------------------------------------------------
// K1: projections. C[16384x512] = X[16384x512] @ W[512x512], per mat in z.
// Block 512 thr (8 waves, 2x4), tile 128x256, BK=32.
// Q,K stored bf16 [b,h,sq,hd]; V stored transposed bf16 [b,h,hd,sk].
// ---------------------------------------------------------------------------
__global__ __launch_bounds__(512) void k_proj(
    const float* __restrict__ Xq, const float* __restrict__ Xk, const float* __restrict__ Xv,
    const u16* __restrict__ Wt,
    u16* __restrict__ Qb, u16* __restrict__ Kb, u16* __restrict__ Vtb) {
  __shared__ u16 lA[128][40];
  __shared__ u16 lB[256][40];
  const int mat = blockIdx.z;
  const float* __restrict__ A = (mat == 0) ? Xq : (mat == 1) ? Xk : Xv;
  const u16* __restrict__ Bw = Wt + (size_t)mat * 262144;
  const int tid = threadIdx.x;
  const int lane = tid & 63, wid = tid >> 6;
  const int wm = wid >> 2, wn = wid & 3;       // wave grid 2 x 4
  const int m0 = blockIdx.y * 128, n0 = blockIdx.x * 256;
  const int fr = lane & 15, g = lane >> 4;
  const int arow = tid >> 3, acg = tid & 7;
  f32x4 acc[4][4] = {};

  for (int kt = 0; kt < 16; ++kt) {
    const int k0 = kt * 32;
#pragma unroll
    for (int p = 0; p < 2; ++p) {              // A: fp32 -> bf16 reg-stage
      int row = p * 64 + arow;
      f32x4 v = *(const f32x4*)&A[(size_t)(m0 + row) * 512 + k0 + acg * 4];
      u16x4 hv;
      hv[0] = f2bf(v[0]); hv[1] = f2bf(v[1]); hv[2] = f2bf(v[2]); hv[3] = f2bf(v[3]);
      *(u16x4*)&lA[row][acg * 4] = hv;
    }
#pragma unroll
    for (int p = 0; p < 2; ++p) {              // B: bf16 copy (row-major [n][k])
      int idx = p * 512 + tid;
      int row = idx >> 2, cg = idx & 3;
      *(u16x8*)&lB[row][cg * 8] = *(const u16x8*)&Bw[(size_t)(n0 + row) * 512 + k0 + cg * 8];
    }
    __syncthreads();
    bf16x8 af[4], bfr[4];
#pragma unroll
    for (int fm = 0; fm < 4; ++fm)
      af[fm] = *(const bf16x8*)&lA[wm * 64 + fm * 16 + fr][g * 8];
#pragma unroll
    for (int fn = 0; fn < 4; ++fn)
      bfr[fn] = *(const bf16x8*)&lB[wn * 64 + fn * 16 + fr][g * 8];
#pragma unroll
    for (int fm = 0; fm < 4; ++fm)
#pragma unroll
      for (int fn = 0; fn < 4; ++fn)
        acc[fm][fn] = MFMA16(af[fm], bfr[fn], acc[fm][fn]);
    __syncthreads();
  }

  if (mat < 2) {
    u16* __restrict__ Out = (mat == 0) ? Qb : Kb;
#pragma unroll
    for (int fm = 0; fm < 4; ++fm) {
#pragma unroll
      for (int fn = 0; fn < 4; ++fn) {
        int gn = n0 + wn * 64 + fn * 16 + fr;
        int hh = gn >> 6, hd = gn & 63;
#pragma unroll
        for (int r = 0; r < 4; ++r) {
          int gm = m0 + wm * 64 + fm * 16 + g * 4 + r;
          int b = gm >> 9, sq = gm & 511;
          Out[(size_t)((b * 8 + hh) * 512 + sq) * 64 + hd] = f2bf(acc[fm][fn][r]);
        }
      }
    }
  } else {
#pragma unroll
    for (int fm = 0; fm < 4; ++fm) {
      int gm0 = m0 + wm * 64 + fm * 16 + g * 4;
      int b = gm0 >> 9, sq0 = gm0 & 511;
#pragma unroll
      for (int fn = 0; fn < 4; ++fn) {
        int gn = n0 + wn * 64 + fn * 16 + fr;
        int hh = gn >> 6, hd = gn & 63;
        u16x4 pv;
        pv[0] = f2bf(acc[fm][fn][0]); pv[1] = f2bf(acc[fm][fn][1]);
        pv[2] = f2bf(acc[fm][fn][2]); pv[3] = f2bf(acc[fm][fn][3]);
        *(u16x4*)&Vtb[(size_t)((b * 8 + hh) * 64 + hd) * 512 + sq0] = pv;
      }
    }
  }
}

// ---------------------------------------------------------------------------
// K2: attention, swapped QK^T. 4 waves x 32 q-rows = 128 q-rows/block,
// grid = 32b x 8h x 4qq = 1024 (4/CU, LDS 40KB). K/V tiles staged to LDS via
// global_load_lds (16B), double-buffered 2-phase: stage(kt+1) issued before
// compute(kt), drained by __syncthreads()'s vmcnt(0) at iteration end.
// Swizzle both-sides (rule #21): LDS dest linear, global source col ^=
// (row&7)<<4, ds_read applies same XOR -> b128 reads at bank floor.
// Softmax in-lane (swapped layout) + defer-max; P bounced per-frag through
// a 2KB/wave LDS buffer.
// ---------------------------------------------------------------------------
__global__ __launch_bounds__(256, 4) void k_attn(
    const u16* __restrict__ Qb, const u16* __restrict__ Kb, const u16* __restrict__ Vtb,
    const _Float16* __restrict__ MB, float* __restrict__ Obuf) {
  __shared__ __align__(16) u16 kbuf[2][64][64];   // 16KB
  __shared__ __align__(16) u16 vbuf[2][64][64];   // 16KB
  __shared__ __align__(16) u16 lP[4][16][64];     // 8KB
  const int tid = threadIdx.x, lane = tid & 63, w = tid >> 6;
  const int orig = blockIdx.x;
  const int xcd = orig & 7, idx = orig >> 3;      // idx 0..127
  const int qq = idx & 3, h = (idx >> 2) & 7;     // q-quarter, head
  const int b = xcd + 8 * (idx >> 5);             // b slow-varying per XCD
  const int bh = b * 8 + h;
  const int fr = lane & 15, g = lane >> 4;
  const int sq0 = qq * 128 + w * 32;
  const int sw = (fr & 7) << 4;                   // byte XOR swizzle (read side)
  const u16* __restrict__ Qh = Qb + (size_t)bh * 32768;
  const u16* __restrict__ Kh = Kb + (size_t)bh * 32768;
  const u16* __restrict__ Vh = Vtb + (size_t)bh * 32768;
  const _Float16* __restrict__ MBr = MB + (size_t)b * 262144 + (size_t)(sq0 + fr) * 512;
  char* lProw = (char*)&lP[w][fr][0];
  const char* kcb;
  const char* vcb;

  // staging geometry: lane l covers LDS row (l>>3), 16B chunk (l&7) of a
  // 1KB (8-row) chunk; global col pre-swizzled so reads can XOR (row&7)<<4.
  const int sub = lane >> 3;                      // 0..7
  const int xo = ((lane & 7) ^ sub) * 8;          // swizzled col (elems)

  // Q fragments (B operand): row = sq0+qfi*16+fr, k = kc*32+g*8
  bf16x8 qf[2][2];
#pragma unroll
  for (int qfi = 0; qfi < 2; ++qfi)
#pragma unroll
    for (int kc = 0; kc < 2; ++kc)
      qf[qfi][kc] = *(const bf16x8*)&Qh[(size_t)(sq0 + qfi * 16 + fr) * 64 + kc * 32 + g * 8];

  f32x4 oacc[2][4] = {};
  float mrow[2] = {-1e30f, -1e30f}, lrow[2] = {0.f, 0.f};

  // prologue: stage tile 0
  {
    if (w < 2) {
      const int rb = w * 32;
      const u16* gs = Kh + (size_t)(rb + sub) * 64 + xo;
#pragma unroll
      for (int i = 0; i < 4; ++i)
        gl_lds16(gs + (size_t)i * 8 * 64, &kbuf[0][rb + i * 8][0]);
    } else {
      const int rb = (w - 2) * 32;
      const u16* gs = Vh + (size_t)(rb + sub) * 512 + xo;
#pragma unroll
      for (int i = 0; i < 4; ++i)
        gl_lds16(gs + (size_t)i * 8 * 512, &vbuf[0][rb + i * 8][0]);
    }
  }
  __syncthreads();

  int cur = 0;
  for (int kt = 0; kt < 8; ++kt) {
    const int sk0 = kt * 64;
    // masked-bias loads FIRST (so their waitcnt is a counted vmcnt, leaving
    // the stage prefetch below in flight)
    f16x4 mbv[2][4];
#pragma unroll
    for (int qfi = 0; qfi < 2; ++qfi)
#pragma unroll
      for (int fn = 0; fn < 4; ++fn)
        mbv[qfi][fn] = *(const f16x4*)&MBr[(size_t)qfi * 16 * 512 + sk0 + fn * 16 + g * 4];
    // prefetch next K/V tile into the other buffer
    if (kt < 7) {
      const int nb = cur ^ 1, sk0n = sk0 + 64;
      if (w < 2) {
        const int rb = w * 32;
        const u16* gs = Kh + (size_t)(sk0n + rb + sub) * 64 + xo;
#pragma unroll
        for (int i = 0; i < 4; ++i)
          gl_lds16(gs + (size_t)i * 8 * 64, &kbuf[nb][rb + i * 8][0]);
      } else {
        const int rb = (w - 2) * 32;
        const u16* gs = Vh + (size_t)(rb + sub) * 512 + sk0n + xo;
#pragma unroll
        for (int i = 0; i < 4; ++i)
          gl_lds16(gs + (size_t)i * 8 * 512, &vbuf[nb][rb + i * 8][0]);
      }
    }
    kcb = (const char*)kbuf[cur];
    vcb = (const char*)vbuf[cur];
    // QK^T swapped: lane holds q = sq0+qfi*16+fr (col), sk = fn*16+g*4+r (row)
    f32x4 sacc[2][4] = {};
#pragma unroll
    for (int fn = 0; fn < 4; ++fn) {
      const int r = fn * 16 + fr;
      bf16x8 kf0 = *(const bf16x8*)(kcb + (size_t)r * 128 + ((0 * 64 + g * 16) ^ sw));
      bf16x8 kf1 = *(const bf16x8*)(kcb + (size_t)r * 128 + ((1 * 64 + g * 16) ^ sw));
      sacc[0][fn] = MFMA16(kf0, qf[0][0], sacc[0][fn]);
      sacc[0][fn] = MFMA16(kf1, qf[0][1], sacc[0][fn]);
      sacc[1][fn] = MFMA16(kf0, qf[1][0], sacc[1][fn]);
      sacc[1][fn] = MFMA16(kf1, qf[1][1], sacc[1][fn]);
    }
    // scale + masked bias
#pragma unroll
    for (int qfi = 0; qfi < 2; ++qfi)
#pragma unroll
      for (int fn = 0; fn < 4; ++fn)
#pragma unroll
        for (int r = 0; r < 4; ++r)
          sacc[qfi][fn][r] = sacc[qfi][fn][r] * 0.125f + (float)mbv[qfi][fn][r];

    // per-frag: online softmax + P bounce + PV (sequential frags share lP)
#pragma unroll
    for (int qfi = 0; qfi < 2; ++qfi) {
      float t0 = fmaxf(fmaxf(sacc[qfi][0][0], sacc[qfi][0][1]),
                       fmaxf(sacc[qfi][0][2], sacc[qfi][0][3]));
      float t1 = fmaxf(fmaxf(sacc[qfi][1][0], sacc[qfi][1][1]),
                       fmaxf(sacc[qfi][1][2], sacc[qfi][1][3]));
      float t2 = fmaxf(fmaxf(sacc[qfi][2][0], sacc[qfi][2][1]),
                       fmaxf(sacc[qfi][2][2], sacc[qfi][2][3]));
      float t3 = fmaxf(fmaxf(sacc[qfi][3][0], sacc[qfi][3][1]),
                       fmaxf(sacc[qfi][3][2], sacc[qfi][3][3]));
      float pm = fmaxf(fmaxf(t0, t1), fmaxf(t2, t3));
      pm = fmaxf(pm, __shfl_xor(pm, 16));
      pm = fmaxf(pm, __shfl_xor(pm, 32));
      if (!__all(pm - mrow[qfi] <= 8.0f)) {     // defer-max (T13)
        float mn = fmaxf(mrow[qfi], pm);
        float sfac = __expf(mrow[qfi] - mn);
        mrow[qfi] = mn;
        lrow[qfi] *= sfac;
#pragma unroll
        for (int r = 0; r < 4; ++r) {
          float sr = __shfl(sfac, g * 4 + r);   // sfac uniform across g
#pragma unroll
          for (int fnh = 0; fnh < 4; ++fnh)
            oacc[qfi][fnh][r] *= sr;
        }
      }
      float ps = 0.f;
#pragma unroll
      for (int fn = 0; fn < 4; ++fn) {
        float p0 = __expf(sacc[qfi][fn][0] - mrow[qfi]);
        float p1 = __expf(sacc[qfi][fn][1] - mrow[qfi]);
        float p2 = __expf(sacc[qfi][fn][2] - mrow[qfi]);
        float p3 = __expf(sacc[qfi][fn][3] - mrow[qfi]);
        ps += (p0 + p1) + (p2 + p3);
        u16x4 pw;
        pw[0] = f2bf(p0); pw[1] = f2bf(p1); pw[2] = f2bf(p2); pw[3] = f2bf(p3);
        *(u16x4*)(lProw + ((fn * 32 + g * 8) ^ sw)) = pw;
      }
      ps += __shfl_xor(ps, 16);
      ps += __shfl_xor(ps, 32);
      lrow[qfi] += ps;
      __builtin_amdgcn_wave_barrier();   // P writes before P reads (wave-private)
#pragma unroll
      for (int kc = 0; kc < 2; ++kc) {
        bf16x8 pf = *(const bf16x8*)(lProw + ((kc * 64 + g * 16) ^ sw));
#pragma unroll
        for (int fnh = 0; fnh < 4; ++fnh) {
          const int vr = fnh * 16 + fr;
          bf16x8 vf = *(const bf16x8*)(vcb + (size_t)vr * 128 + ((kc * 64 + g * 16) ^ sw));
          oacc[qfi][fnh] = MFMA16(pf, vf, oacc[qfi][fnh]);
        }
      }
      __builtin_amdgcn_wave_barrier();   // next frag's P writes after these reads
    }
    __syncthreads();   // drains stage prefetch (vmcnt 0) + tile handoff
    cur ^= 1;
  }
  // epilogue: O / l -> Obuf[b, sq, h*64+hd] fp32 (oacc: q = g*4+r, d = fnh*16+fr)
#pragma unroll
  for (int qfi = 0; qfi < 2; ++qfi) {
#pragma unroll
    for (int r = 0; r < 4; ++r) {
      float lr = __shfl(lrow[qfi], g * 4 + r);
      float inv = 1.0f / lr;
      const int sq = sq0 + qfi * 16 + g * 4 + r;
      float* orow = &Obuf[((size_t)b * 512 + sq) * 512 + h * 64];
#pragma unroll
      for (int fnh = 0; fnh < 4; ++fnh)
        orow[fnh * 16 + fr] = oacc[qfi][fnh][r] * inv;
    }
  }
}

// ---------------------------------------------------------------------------
// K3: output projection with 2-term bf16 split (hi/lo) for fp32-level accuracy:
// C = Oh@Wh + Oh@Wl + Ol@Wh + bo. Tile 128x256, 8 waves.
// ---------------------------------------------------------------------------
__global__ __launch_bounds__(512) void k_out(
    const float* __restrict__ Oin, const u16* __restrict__ WoHi, const u16* __restrict__ WoLo,
    const float* __restrict__ bo, float* __restrict__ out) {
  __shared__ u16 lAh[128][40], lAl[128][40];
  __shared__ u16 lBh[256][40], lBl[256][40];
  const int tid = threadIdx.x;
  const int lane = tid & 63, wid = tid >> 6;
  const int wm = wid >> 2, wn = wid & 3;
  const int m0 = blockIdx.y * 128, n0 = blockIdx.x * 256;
  const int fr = lane & 15, g = lane >> 4;
  const int arow = tid >> 3, acg = tid & 7;
  f32x4 acc[4][4] = {};

  for (int kt = 0; kt < 16; ++kt) {
    const int k0 = kt * 32;
#pragma unroll
    for (int p = 0; p < 2; ++p) {
      int row = p * 64 + arow;
      f32x4 v = *(const f32x4*)&Oin[(size_t)(m0 + row) * 512 + k0 + acg * 4];
      u16x4 hv, lv;
#pragma unroll
      for (int e = 0; e < 4; ++e) {
        u16 hb = f2bf(v[e]);
        hv[e] = hb;
        lv[e] = f2bf(v[e] - bf2f(hb));
      }
      *(u16x4*)&lAh[row][acg * 4] = hv;
      *(u16x4*)&lAl[row][acg * 4] = lv;
    }
#pragma unroll
    for (int p = 0; p < 2; ++p) {
      int idx = p * 512 + tid;
      int row = idx >> 2, cg = idx & 3;
      *(u16x8*)&lBh[row][cg * 8] = *(const u16x8*)&WoHi[(size_t)(n0 + row) * 512 + k0 + cg * 8];
      *(u16x8*)&lBl[row][cg * 8] = *(const u16x8*)&WoLo[(size_t)(n0 + row) * 512 + k0 + cg * 8];
    }
    __syncthreads();
    bf16x8 ah[4], al[4];
#pragma unroll
    for (int fm = 0; fm < 4; ++fm) {
      ah[fm] = *(const bf16x8*)&lAh[wm * 64 + fm * 16 + fr][g * 8];
      al[fm] = *(const bf16x8*)&lAl[wm * 64 + fm * 16 + fr][g * 8];
    }
#pragma unroll
    for (int fn = 0; fn < 4; ++fn) {
      bf16x8 bh = *(const bf16x8*)&lBh[wn * 64 + fn * 16 + fr][g * 8];
      bf16x8 bl = *(const bf16x8*)&lBl[wn * 64 + fn * 16 + fr][g * 8];
#pragma unroll
      for (int fm = 0; fm < 4; ++fm) {
        acc[fm][fn] = MFMA16(ah[fm], bh, acc[fm][fn]);
        acc[fm][fn] = MFMA16(ah[fm], bl, acc[fm][fn]);
        acc[fm][fn] = MFMA16(al[fm], bh, acc[fm][fn]);
      }
    }
    __syncthreads();
  }
#pragma unroll
  for (int fm = 0; fm < 4; ++fm) {
#pragma unroll
    for (int fn = 0; fn < 4; ++fn) {
      int gn = n0 + wn * 64 + fn * 16 + fr;
      float bv = bo[gn];
#pragma unroll
      for (int r = 0; r < 4; ++r) {
        int gm = m0 + wm * 64 + fm * 16 + g * 4 + r;
        out[(size_t)gm * 512 + gn] = acc[fm][fn][r] + bv;
      }
    }
  }
}

// ---------------------------------------------------------------------------
extern "C" void kernel_launch(void* const* d_in, const int* in_sizes, int n_in,
                              void* d_out, int out_size, void* d_ws, size_t ws_size,
                              hipStream_t stream) {
  (void)in_sizes; (void)n_in; (void)out_size; (void)ws_size;
  const float* query = (const float*)d_in[0];
  const float* key_t = (const float*)d_in[1];
  const float* value = (const float*)d_in[2];
  const int*   mask  = (const int*)d_in[3];
  const float* Wq    = (const float*)d_in[4];
  const float* Wk    = (const float*)d_in[5];
  const float* Wv    = (const float*)d_in[6];
  const float* Wo    = (const float*)d_in[7];
  const float* bo    = (const float*)d_in[8];
  const float* bias  = (const float*)d_in[9];
  float* out = (float*)d_out;

  char* p = (char*)d_ws;
  u16* Wt   = (u16*)p; p += (size_t)3 * 512 * 512 * 2;       // 1.5 MB
  u16* WoHi = (u16*)p; p += (size_t)512 * 512 * 2;           // 0.5 MB
  u16* WoLo = (u16*)p; p += (size_t)512 * 512 * 2;           // 0.5 MB
  u16* Qb   = (u16*)p; p += (size_t)32 * 8 * 512 * 64 * 2;   // 16.8 MB
  u16* Kb   = (u16*)p; p += (size_t)32 * 8 * 512 * 64 * 2;   // 16.8 MB
  u16* Vtb  = (u16*)p; p += (size_t)32 * 8 * 512 * 64 * 2;   // 16.8 MB
  float* Obuf = (float*)p; p += (size_t)32 * 512 * 512 * 4;  // 33.5 MB
  _Float16* MBp = (_Float16*)p;                              // 16.8 MB (total ~103.6 MB)

  k_prep<<<1024, 256, 0, stream>>>(Wq, Wk, Wv, Wo, Wt, WoHi, WoLo);
  k_mb<<<4096, 256, 0, stream>>>(mask, bias, MBp);
  k_proj<<<dim3(2, 128, 3), 512, 0, stream>>>(query, key_t, value, Wt, Qb, Kb, Vtb);
  k_attn<<<1024, 256, 0, stream>>>(Qb, Kb, Vtb, MBp, Obuf);
  k_out<<<dim3(2, 128), 512, 0, stream>>>(Obuf, WoHi, WoLo, bo, out);
}